// Round 9
// baseline (161.288 us; speedup 1.0000x reference)
//
#include <hip/hip_runtime.h>

constexpr int DIN  = 128;
constexpr int DOUT = 128;
constexpr float EPS_SCALE = 1e-7f;

typedef __attribute__((ext_vector_type(8))) short bf16x8;
typedef __attribute__((ext_vector_type(4))) float f32x4;

__device__ __forceinline__ float lrelu(float x) { return fmaxf(x, 0.01f * x); }

__device__ __forceinline__ unsigned short f2bf(float x) {
    unsigned u = __float_as_uint(x);
    unsigned r = (u + 0x7FFFu + ((u >> 16) & 1u)) >> 16;   // RNE
    return (unsigned short)r;
}
__device__ __forceinline__ float bf2f(unsigned short h) {
    return __uint_as_float(((unsigned)h) << 16);
}

// ---------------------------------------------------------------------------
// 1) Fused prep: hist(dst) | feat fp32->bf16 | pack W frags + combined bias.
// ---------------------------------------------------------------------------
__global__ __launch_bounds__(256) void prep_kernel(
    const int* __restrict__ dst, int* __restrict__ hist, int E, int eb,
    const float* __restrict__ feat, unsigned short* __restrict__ featbf,
    int total8, int cb,
    const float* __restrict__ Wself, const float* __restrict__ Wneigh,
    const float* __restrict__ b_self, const float* __restrict__ b_neigh,
    const float* __restrict__ bias,
    unsigned short* __restrict__ bfrag, float* __restrict__ bb)
{
    int b = blockIdx.x;
    int tid = threadIdx.x;
    if (b < eb) {
        int e = b * 256 + tid;
        if (e < E) atomicAdd(&hist[dst[e]], 1);
    } else if (b < eb + cb) {
        int i = (b - eb) * 256 + tid;          // handles 8 floats
        if (i < total8) {
            float4 v0 = *(const float4*)(feat + (size_t)i * 8);
            float4 v1 = *(const float4*)(feat + (size_t)i * 8 + 4);
            bf16x8 o;
            o[0] = (short)f2bf(v0.x); o[1] = (short)f2bf(v0.y);
            o[2] = (short)f2bf(v0.z); o[3] = (short)f2bf(v0.w);
            o[4] = (short)f2bf(v1.x); o[5] = (short)f2bf(v1.y);
            o[6] = (short)f2bf(v1.z); o[7] = (short)f2bf(v1.w);
            *(bf16x8*)(featbf + (size_t)i * 8) = o;
        }
    } else {
        int idx = (b - eb - cb) * 256 + tid;   // 0..32767
        if (idx < 32768) {
            int j = idx & 7;
            int l = (idx >> 3) & 63;
            int f = (idx >> 9) & 7;
            int s = (idx >> 12) & 7;
            int k = s * 32 + ((l >> 4) << 3) + j;
            int c = f * 16 + (l & 15);
            float v = (k < 128) ? Wself[c * 128 + k] : Wneigh[c * 128 + (k - 128)];
            bfrag[idx] = f2bf(v);
        }
        if (idx < 128) bb[idx] = b_self[idx] + b_neigh[idx] + bias[idx];
    }
}

// ---------------------------------------------------------------------------
// 2a) Per-block partial sums over 1024-elem chunks
// ---------------------------------------------------------------------------
__global__ __launch_bounds__(256) void scan_part1(
    const int* __restrict__ hist, int* __restrict__ bsum, int N)
{
    __shared__ int wsum[4];
    int tid = threadIdx.x, wave = tid >> 6, lane = tid & 63;
    int idx = blockIdx.x * 1024 + tid * 4;
    int4 h = make_int4(0, 0, 0, 0);
    if (idx < N) h = *(const int4*)(hist + idx);
    int s = h.x + h.y + h.z + h.w;
#pragma unroll
    for (int off = 1; off < 64; off <<= 1) s += __shfl_xor(s, off, 64);
    if (lane == 0) wsum[wave] = s;
    __syncthreads();
    if (tid == 0) bsum[blockIdx.x] = wsum[0] + wsum[1] + wsum[2] + wsum[3];
}

// ---------------------------------------------------------------------------
// 2b) Fused block-base + in-block exclusive scan -> rowptr[0..N-1], rowptr[N]=E
//     Wave 0 re-reduces bsum[0..blockIdx.x-1] (nb <= 64).
// ---------------------------------------------------------------------------
__global__ __launch_bounds__(256) void scan_part23(
    const int* __restrict__ hist, const int* __restrict__ bsum, int nb,
    int* __restrict__ rowptr, int N, int E)
{
    __shared__ int wsum[4];
    __shared__ int base_s;
    int tid = threadIdx.x, wave = tid >> 6, lane = tid & 63;

    if (wave == 0) {
        int x = (lane < nb && lane < blockIdx.x) ? bsum[lane] : 0;
#pragma unroll
        for (int off = 1; off < 64; off <<= 1) x += __shfl_xor(x, off, 64);
        if (lane == 0) base_s = x;
    }

    int idx = blockIdx.x * 1024 + tid * 4;
    int4 h = make_int4(0, 0, 0, 0);
    if (idx < N) h = *(const int4*)(hist + idx);
    int s = h.x + h.y + h.z + h.w;
    int x = s;
#pragma unroll
    for (int off = 1; off < 64; off <<= 1) {
        int v = __shfl_up(x, off, 64);
        if (lane >= off) x += v;
    }
    if (lane == 63) wsum[wave] = x;
    __syncthreads();
    int wb = 0;
#pragma unroll
    for (int w = 0; w < 4; ++w) if (w < wave) wb += wsum[w];
    int base = base_s + wb + (x - s);
    if (idx < N) {
        rowptr[idx + 0] = base;
        rowptr[idx + 1] = base + h.x;
        rowptr[idx + 2] = base + h.x + h.y;
        rowptr[idx + 3] = base + h.x + h.y + h.z;
    }
    if (blockIdx.x == 0 && tid == 0) rowptr[N] = E;
}

// ---------------------------------------------------------------------------
// 3) Scatter: per-edge spatial coeff (bf16) + src id packed into 8B, CSR order.
//    rec = { c0bf | c1bf<<16 , c2bf | src<<16 }   (requires N < 65536)
// ---------------------------------------------------------------------------
__global__ __launch_bounds__(256) void scatter_kernel(
    const int* __restrict__ dst, const int* __restrict__ src,
    const float* __restrict__ pos,
    const int* __restrict__ rowptr, int* __restrict__ cur,
    uint2* __restrict__ epack, int E)
{
    int e = blockIdx.x * blockDim.x + threadIdx.x;
    if (e < E) {
        int d = dst[e];
        int s = src[e];
        float r0 = pos[d * 3 + 0] - pos[s * 3 + 0];
        float r1 = pos[d * 3 + 1] - pos[s * 3 + 1];
        float r2 = pos[d * 3 + 2] - pos[s * 3 + 2];
        float inv = 1.0f / (sqrtf(r0 * r0 + r1 * r1 + r2 * r2) + EPS_SCALE);
        unsigned c0 = f2bf((r0 + 1.0f) * inv);
        unsigned c1 = f2bf((r1 + 1.0f) * inv);
        unsigned c2 = f2bf((r2 + 1.0f) * inv);
        int p = atomicAdd(&cur[d], 1);
        epack[rowptr[d] + p] = make_uint2(c0 | (c1 << 16),
                                          c2 | ((unsigned)s << 16));
    }
}

// ---------------------------------------------------------------------------
// 4) Gather: persistent waves, 3x-unrolled quarter loop -> 12 independent
//    edge load-chains per wave. Quarter q owns edges start+q (step 4);
//    sl = lane&15 owns dims sl*8..sl*8+7.
// ---------------------------------------------------------------------------
#define EDGE_FMA(R, F)                                                           \
    do {                                                                         \
        float c0 = __uint_as_float(R.x << 16);                                   \
        float c1 = __uint_as_float(R.x & 0xffff0000u);                           \
        float c2 = __uint_as_float(R.y << 16);                                   \
        a0 = fmaf(lrelu(fmaf(c0, w0.x, fmaf(c1, w0.y, fmaf(c2, w0.z, b0.x)))),   \
                  bf2f((unsigned short)F[0]), a0);                               \
        a1 = fmaf(lrelu(fmaf(c0, w0.w, fmaf(c1, w1.x, fmaf(c2, w1.y, b0.y)))),   \
                  bf2f((unsigned short)F[1]), a1);                               \
        a2 = fmaf(lrelu(fmaf(c0, w1.z, fmaf(c1, w1.w, fmaf(c2, w2.x, b0.z)))),   \
                  bf2f((unsigned short)F[2]), a2);                               \
        a3 = fmaf(lrelu(fmaf(c0, w2.y, fmaf(c1, w2.z, fmaf(c2, w2.w, b0.w)))),   \
                  bf2f((unsigned short)F[3]), a3);                               \
        a4 = fmaf(lrelu(fmaf(c0, w3.x, fmaf(c1, w3.y, fmaf(c2, w3.z, b1.x)))),   \
                  bf2f((unsigned short)F[4]), a4);                               \
        a5 = fmaf(lrelu(fmaf(c0, w3.w, fmaf(c1, w4.x, fmaf(c2, w4.y, b1.y)))),   \
                  bf2f((unsigned short)F[5]), a5);                               \
        a6 = fmaf(lrelu(fmaf(c0, w4.z, fmaf(c1, w4.w, fmaf(c2, w5.x, b1.z)))),   \
                  bf2f((unsigned short)F[6]), a6);                               \
        a7 = fmaf(lrelu(fmaf(c0, w5.y, fmaf(c1, w5.z, fmaf(c2, w5.w, b1.w)))),   \
                  bf2f((unsigned short)F[7]), a7);                               \
    } while (0)

__global__ __launch_bounds__(256) void gather_kernel(
    const unsigned short* __restrict__ featbf,
    const uint2* __restrict__ epack,
    const int*   __restrict__ rowptr,
    const float* __restrict__ Wsp,   // [128][3]
    const float* __restrict__ bsp,   // [128]
    unsigned short* __restrict__ hmbf,  // [N][128]
    int N, int nwaves)
{
    int gw   = (blockIdx.x * 256 + threadIdx.x) >> 6;
    int lane = threadIdx.x & 63;
    int q    = lane >> 4;
    int sl   = lane & 15;
    int d    = sl * 8;

    const float4* wp = (const float4*)(Wsp + d * 3);
    float4 w0 = wp[0], w1 = wp[1], w2 = wp[2];
    float4 w3 = wp[3], w4 = wp[4], w5 = wp[5];
    float4 b0 = *(const float4*)(bsp + d);
    float4 b1 = *(const float4*)(bsp + d + 4);

    const unsigned short* fb = featbf + d;

    for (int v = gw; v < N; v += nwaves) {
        int start = rowptr[v];
        int end   = rowptr[v + 1];

        float a0 = 0.f, a1 = 0.f, a2 = 0.f, a3 = 0.f;
        float a4 = 0.f, a5 = 0.f, a6 = 0.f, a7 = 0.f;

        int i = start + q;
        for (; i + 8 < end; i += 12) {
            uint2 rA = epack[i];
            uint2 rB = epack[i + 4];
            uint2 rC = epack[i + 8];
            bf16x8 fA = *(const bf16x8*)(fb + (size_t)(rA.y >> 16) * DIN);
            bf16x8 fB = *(const bf16x8*)(fb + (size_t)(rB.y >> 16) * DIN);
            bf16x8 fC = *(const bf16x8*)(fb + (size_t)(rC.y >> 16) * DIN);
            EDGE_FMA(rA, fA);
            EDGE_FMA(rB, fB);
            EDGE_FMA(rC, fC);
        }
        for (; i < end; i += 4) {
            uint2 rA = epack[i];
            bf16x8 fA = *(const bf16x8*)(fb + (size_t)(rA.y >> 16) * DIN);
            EDGE_FMA(rA, fA);
        }

        a0 += __shfl_xor(a0, 16); a0 += __shfl_xor(a0, 32);
        a1 += __shfl_xor(a1, 16); a1 += __shfl_xor(a1, 32);
        a2 += __shfl_xor(a2, 16); a2 += __shfl_xor(a2, 32);
        a3 += __shfl_xor(a3, 16); a3 += __shfl_xor(a3, 32);
        a4 += __shfl_xor(a4, 16); a4 += __shfl_xor(a4, 32);
        a5 += __shfl_xor(a5, 16); a5 += __shfl_xor(a5, 32);
        a6 += __shfl_xor(a6, 16); a6 += __shfl_xor(a6, 32);
        a7 += __shfl_xor(a7, 16); a7 += __shfl_xor(a7, 32);

        if (q == 0) {
            float invd = 1.0f / fmaxf((float)(end - start), 1.0f);
            bf16x8 o;
            o[0] = (short)f2bf(a0 * invd); o[1] = (short)f2bf(a1 * invd);
            o[2] = (short)f2bf(a2 * invd); o[3] = (short)f2bf(a3 * invd);
            o[4] = (short)f2bf(a4 * invd); o[5] = (short)f2bf(a5 * invd);
            o[6] = (short)f2bf(a6 * invd); o[7] = (short)f2bf(a7 * invd);
            *(bf16x8*)(hmbf + (size_t)v * DIN + d) = o;
        }
    }
}

// ---------------------------------------------------------------------------
// 5) Node GEMM via MFMA: out = lrelu([featbf | hmbf] @ Wc^T + bb)
// ---------------------------------------------------------------------------
__global__ __launch_bounds__(256) void node_mfma_kernel(
    const unsigned short* __restrict__ featbf,
    const unsigned short* __restrict__ hmbf,
    const unsigned short* __restrict__ bfrag,
    const float* __restrict__ bb,
    float* __restrict__ out, int N)
{
    int wave = threadIdx.x >> 6;
    int lane = threadIdx.x & 63;
    int r0   = blockIdx.x * 64 + wave * 16;
    int row  = r0 + (lane & 15);
    bool rowok = row < N;
    int kb = (lane >> 4) << 3;

    f32x4 acc[8];
#pragma unroll
    for (int f = 0; f < 8; ++f) acc[f] = (f32x4)0.0f;

#pragma unroll
    for (int s = 0; s < 8; ++s) {
        bf16x8 a = (bf16x8)(short)0;
        if (rowok) {
            const unsigned short* base =
                (s < 4 ? featbf : hmbf) + (size_t)row * DIN + (s & 3) * 32 + kb;
            a = *(const bf16x8*)base;
        }
#pragma unroll
        for (int f = 0; f < 8; ++f) {
            bf16x8 b = *(const bf16x8*)(bfrag + ((((s * 8 + f) * 64) + lane) * 8));
            acc[f] = __builtin_amdgcn_mfma_f32_16x16x32_bf16(a, b, acc[f], 0, 0, 0);
        }
    }

    int crow = r0 + ((lane >> 4) << 2);
    int col  = lane & 15;
#pragma unroll
    for (int f = 0; f < 8; ++f) {
        int c = f * 16 + col;
        float bbv = bb[c];
#pragma unroll
        for (int r = 0; r < 4; ++r) {
            int rr = crow + r;
            if (rr < N) out[(size_t)rr * DOUT + c] = lrelu(acc[f][r] + bbv);
        }
    }
}

// ---------------------------------------------------------------------------
extern "C" void kernel_launch(void* const* d_in, const int* in_sizes, int n_in,
                              void* d_out, int out_size, void* d_ws, size_t ws_size,
                              hipStream_t stream)
{
    const float* feat    = (const float*)d_in[0];
    const float* pos     = (const float*)d_in[1];
    const int*   src     = (const int*)  d_in[2];
    const int*   dst     = (const int*)  d_in[3];
    const float* Wsp     = (const float*)d_in[4];
    const float* bsp     = (const float*)d_in[5];
    const float* Wneigh  = (const float*)d_in[6];
    const float* b_neigh = (const float*)d_in[7];
    const float* Wself   = (const float*)d_in[8];
    const float* b_self  = (const float*)d_in[9];
    const float* bias    = (const float*)d_in[10];

    int N = in_sizes[0] / DIN;
    int E = in_sizes[2];
    int nb = (N + 1023) / 1024;   // scan blocks (49 for N=50000; <= 64)

    // Workspace layout (all 16B aligned):
    // featbf [N*128 u16] | hmbf [N*128 u16] | epack [E uint2] | bfrag [32768 u16]
    // | bb [128 f32] | hist [N] | cur [N] | rowptr [N+4] | bsum [64]
    char* p = (char*)d_ws;
    unsigned short* featbf = (unsigned short*)p; p += (size_t)N * DIN * 2;
    unsigned short* hmbf   = (unsigned short*)p; p += (size_t)N * DIN * 2;
    uint2* epack           = (uint2*)p;          p += (size_t)E * 8;
    unsigned short* bfrag  = (unsigned short*)p; p += 32768 * 2;
    float* bb              = (float*)p;          p += 128 * 4;
    int* hist              = (int*)p;            p += (size_t)N * 4;
    int* cur               = (int*)p;            p += (size_t)N * 4;
    int* rowptr            = (int*)p;            p += (size_t)(N + 4) * 4;
    int* bsum              = (int*)p;

    // zero hist + cur (adjacent)
    hipMemsetAsync(hist, 0, (size_t)2 * N * sizeof(int), stream);

    int eb = (E + 255) / 256;            // hist blocks
    int cb = (N * 16 + 255) / 256;       // convert blocks (N*128/8 threads)
    int pb = 129;                        // pack blocks
    prep_kernel<<<eb + cb + pb, 256, 0, stream>>>(
        dst, hist, E, eb, feat, featbf, N * 16, cb,
        Wself, Wneigh, b_self, b_neigh, bias, bfrag, bb);

    scan_part1<<<nb, 256, 0, stream>>>(hist, bsum, N);
    scan_part23<<<nb, 256, 0, stream>>>(hist, bsum, nb, rowptr, N, E);

    scatter_kernel<<<eb, 256, 0, stream>>>(dst, src, pos, rowptr, cur, epack, E);

    int gblocks = 2048;
    gather_kernel<<<gblocks, 256, 0, stream>>>(featbf, epack, rowptr, Wsp, bsp,
                                               hmbf, N, gblocks * 4);

    node_mfma_kernel<<<(N + 63) / 64, 256, 0, stream>>>(featbf, hmbf, bfrag, bb,
                                                        (float*)d_out, N);
}